// Round 2
// baseline (1035.741 us; speedup 1.0000x reference)
//
#include <hip/hip_runtime.h>

#define TT 512
#define BB 512
#define II 8
#define HH 256
#define ST 296   // padded LDS row stride (halfs): 592B, breaks pow2 bank patterns

typedef _Float16 h4_t  __attribute__((ext_vector_type(4)));
typedef _Float16 h8_t  __attribute__((ext_vector_type(8)));
typedef float    f32x4 __attribute__((ext_vector_type(4)));

__device__ inline h8_t cvt8(const float* __restrict__ p, float s) {
    h8_t r;
#pragma unroll
    for (int i = 0; i < 8; ++i) r[i] = (_Float16)(p[i] * s);
    return r;
}

// Persistent GRU: 32 blocks x 512 threads (8 waves = 2 waves/SIMD).
// R3 restructure, from R2 counters (dur 994us = 4460 cyc/step; per-active-CU
// VALUBusy ~46%, DS pipe ~900 cyc/step from 68 ds_reads/SIMD/step, MFMA only
// ~540): with 16 waves the 128-VGPR cap forced 1/3 of W_hh into LDS (wnbuf)
// and phases serialize at the barrier, so pipe demands ADD. At 8 waves the
// cap is 256 VGPRs: each wave owns 2 col-groups (6 chains); 5 chains' W live
// in registers (160 VGPRs), 1 chain in a 64KB LDS pool; A-fragments are read
// ONCE per step and reused by all 6 chains. DS reads/SIMD/step drop ~2.3x,
// barrier population halves, 6 interleaved chains feed the MFMA pipe.
// Liveness budget: W 160 + xf 12 + hreg 8 + acc 24 + a/wn 10 + misc ~12
// ~= 226 < 256 (launch_bounds(512,2)).
__global__ void __launch_bounds__(512, 2) gru_kernel(
    const float* __restrict__ x,    const float* __restrict__ W_ih,
    const float* __restrict__ W_hh, const float* __restrict__ b_ih,
    const float* __restrict__ b_hh, const float* __restrict__ W_lin,
    const float* __restrict__ b_lin, float* __restrict__ out)
{
    __shared__ _Float16 hbuf[2][16][ST];
    __shared__ _Float16 wlin[HH];
    __shared__ h8_t wn1buf[8 * 8 * 64];   // 64 KiB: group-1 N-gate W frags, lane-private

    const int tid  = threadIdx.x;
    const int w    = tid >> 6;     // wave 0..7
    const int lane = tid & 63;
    const int q    = lane >> 4;    // quad 0..3
    const int r15  = lane & 15;
    const int row0 = blockIdx.x * 16;

    // scales fold log2(e) into the weights:
    //   sigmoid(a) = rcp(1 + exp2(-a*log2e));  tanh(y) = 1 - 2*rcp(1 + exp2(2y*log2e))
    const float sRZ = -1.44269504088896340736f;
    const float sN  =  2.88539008177792681472f;

    // wave w owns gate columns [32w, 32w+32): col-groups g=0,1
    const int c0 = w * 32 + r15;        // group 0 column
    const int c1 = c0 + 16;             // group 1 column

    // ---- W_hh -> B-fragments (16x16x32_f16: lane holds B[n=lane&15][k=q*8+j]) ----
    // 5 chains in regs (R0,Z0,N0,R1,Z1 = 160 VGPRs); N1 -> LDS pool.
    h8_t wfR0[8], wfZ0[8], wfN0[8], wfR1[8], wfZ1[8];
#pragma unroll
    for (int s = 0; s < 8; ++s) {
        const int k0 = s * 32 + q * 8;
        wfR0[s] = cvt8(W_hh + (size_t)(c0)       * HH + k0, sRZ);
        wfZ0[s] = cvt8(W_hh + (size_t)(256 + c0) * HH + k0, sRZ);
        wfN0[s] = cvt8(W_hh + (size_t)(512 + c0) * HH + k0, sN);
        wfR1[s] = cvt8(W_hh + (size_t)(c1)       * HH + k0, sRZ);
        wfZ1[s] = cvt8(W_hh + (size_t)(256 + c1) * HH + k0, sRZ);
        wn1buf[(w * 8 + s) * 64 + lane] = cvt8(W_hh + (size_t)(512 + c1) * HH + k0, sN);
    }
    // ---- x-part B-fragments (16x16x16f16) over [x(8)|bias(1)|0..] for both groups ----
    h4_t xfR[2], xfZ[2], xfN[2];
#pragma unroll
    for (int g = 0; g < 2; ++g) {
        const int cR = g ? c1 : c0;
#pragma unroll
        for (int j = 0; j < 4; ++j) {
            const int kp = q * 4 + j;
            float vR = 0.f, vZ = 0.f, vN = 0.f;
            if (kp < 8) {
                vR = W_ih[(cR)       * II + kp] * sRZ;
                vZ = W_ih[(256 + cR) * II + kp] * sRZ;
                vN = W_ih[(512 + cR) * II + kp] * sN;
            } else if (kp == 8) {
                vR = (b_ih[cR]       + b_hh[cR])       * sRZ;
                vZ = (b_ih[256 + cR] + b_hh[256 + cR]) * sRZ;
                vN = b_ih[512 + cR] * sN;   // b_hh_n rides inside r*(.), kept separate
            }
            xfR[g][j] = (_Float16)vR; xfZ[g][j] = (_Float16)vZ; xfN[g][j] = (_Float16)vN;
        }
    }
    const float bhn0 = b_hh[512 + c0] * sN;
    const float bhn1 = b_hh[512 + c1] * sN;
    const float blin = b_lin[0];

    // ---- LDS init: zero both h buffers, bias-one at k=264, x_0 into buf0 ----
    for (int i = tid; i < 2 * 16 * ST; i += 512) (&hbuf[0][0][0])[i] = (_Float16)0.f;
    if (tid < HH) wlin[tid] = (_Float16)W_lin[tid];
    __syncthreads();
    if (tid < 32) hbuf[tid >> 4][tid & 15][264] = (_Float16)1.f;
    if (tid < 128) {
        const int rr_ = tid >> 3, ii = tid & 7;
        hbuf[0][rr_][256 + ii] = (_Float16)x[((size_t)(row0 + rr_) * TT + 0) * II + ii];
    }
    __syncthreads();

    const h8_t* __restrict__ wn_lane = &wn1buf[w * 8 * 64 + lane];  // frag s at wn_lane[s*64]

    f32x4 hreg0 = {0.f, 0.f, 0.f, 0.f};    // h at (row=q*4+j, col=c0)
    f32x4 hreg1 = {0.f, 0.f, 0.f, 0.f};    // h at (row=q*4+j, col=c1)
    const f32x4 z4 = {0.f, 0.f, 0.f, 0.f};

    // pred assignment: half-wave lanes 0-31 -> row w, lanes 32-63 -> row w+8
    const int prow = w + ((lane >> 5) << 3);
    const int l31  = lane & 31;

    for (int t = 0; t < TT; ++t) {
        const int cur = t & 1, nxt = cur ^ 1;

        // prefetch x_{t+1}: lanes 0-7 carry row w, lanes 32-39 carry row w+8
        float xv = 0.f;
        {
            const int tn = (t + 1 < TT) ? t + 1 : TT - 1;
            const int xr = (lane < II) ? w : ((lane >= 32 && lane < 32 + II) ? w + 8 : -1);
            if (xr >= 0) xv = x[((size_t)(row0 + xr) * TT + tn) * II + (lane & 7)];
        }

        // A-fragments from LDS (A[m=lane&15][k=q*8+j]); 6 fused chains share A
        const _Float16* hb = &hbuf[cur][r15][0];
        const h4_t a2 = *(const h4_t*)(hb + 256 + q * 4);
        f32x4 accR0 = __builtin_amdgcn_mfma_f32_16x16x16f16(a2, xfR[0], z4, 0, 0, 0);
        f32x4 accZ0 = __builtin_amdgcn_mfma_f32_16x16x16f16(a2, xfZ[0], z4, 0, 0, 0);
        f32x4 gin0  = __builtin_amdgcn_mfma_f32_16x16x16f16(a2, xfN[0], z4, 0, 0, 0);
        f32x4 accR1 = __builtin_amdgcn_mfma_f32_16x16x16f16(a2, xfR[1], z4, 0, 0, 0);
        f32x4 accZ1 = __builtin_amdgcn_mfma_f32_16x16x16f16(a2, xfZ[1], z4, 0, 0, 0);
        f32x4 gin1  = __builtin_amdgcn_mfma_f32_16x16x16f16(a2, xfN[1], z4, 0, 0, 0);
        f32x4 accN0 = z4, accN1 = z4;
#pragma unroll
        for (int s = 0; s < 8; ++s) {
            const h8_t a  = *(const h8_t*)(hb + s * 32 + q * 8);   // shared by all 6 chains
            const h8_t wn = wn_lane[s * 64];                       // lane-private b128
            accR0 = __builtin_amdgcn_mfma_f32_16x16x32_f16(a, wfR0[s], accR0, 0, 0, 0);
            accZ0 = __builtin_amdgcn_mfma_f32_16x16x32_f16(a, wfZ0[s], accZ0, 0, 0, 0);
            accN0 = __builtin_amdgcn_mfma_f32_16x16x32_f16(a, wfN0[s], accN0, 0, 0, 0);
            accR1 = __builtin_amdgcn_mfma_f32_16x16x32_f16(a, wfR1[s], accR1, 0, 0, 0);
            accZ1 = __builtin_amdgcn_mfma_f32_16x16x32_f16(a, wfZ1[s], accZ1, 0, 0, 0);
            accN1 = __builtin_amdgcn_mfma_f32_16x16x32_f16(a, wn,     accN1, 0, 0, 0);
        }

        // gates (C/D layout: col=lane&15, row=q*4+j), group 0 then group 1
#pragma unroll
        for (int j = 0; j < 4; ++j) {
            const float rr = __builtin_amdgcn_rcpf(1.f + __builtin_amdgcn_exp2f(accR0[j]));
            const float zz = __builtin_amdgcn_rcpf(1.f + __builtin_amdgcn_exp2f(accZ0[j]));
            const float u  = gin0[j] + rr * (accN0[j] + bhn0);
            const float nn = 1.f - 2.f * __builtin_amdgcn_rcpf(1.f + __builtin_amdgcn_exp2f(u));
            const float hv = nn + zz * (hreg0[j] - nn);
            hreg0[j] = hv;
            hbuf[nxt][q * 4 + j][w * 32 + r15] = (_Float16)hv;
        }
#pragma unroll
        for (int j = 0; j < 4; ++j) {
            const float rr = __builtin_amdgcn_rcpf(1.f + __builtin_amdgcn_exp2f(accR1[j]));
            const float zz = __builtin_amdgcn_rcpf(1.f + __builtin_amdgcn_exp2f(accZ1[j]));
            const float u  = gin1[j] + rr * (accN1[j] + bhn1);
            const float nn = 1.f - 2.f * __builtin_amdgcn_rcpf(1.f + __builtin_amdgcn_exp2f(u));
            const float hv = nn + zz * (hreg1[j] - nn);
            hreg1[j] = hv;
            hbuf[nxt][q * 4 + j][w * 32 + 16 + r15] = (_Float16)hv;
        }
        {
            const int xr = (lane < II) ? w : ((lane >= 32 && lane < 32 + II) ? w + 8 : -1);
            if (xr >= 0) hbuf[nxt][xr][256 + (lane & 7)] = (_Float16)xv;
        }

        __syncthreads();   // single barrier per step: publishes h_t (+x_{t+1}) in buf nxt

        // pred_t = h_t . W_lin + b_lin : half-wave reduces one row (rows w and w+8)
        {
            const h8_t hv8 = *(const h8_t*)&hbuf[nxt][prow][l31 * 8];
            const h8_t wl8 = *(const h8_t*)&wlin[l31 * 8];
            float s0 = 0.f;
#pragma unroll
            for (int i = 0; i < 8; ++i) s0 += (float)hv8[i] * (float)wl8[i];
#pragma unroll
            for (int m = 16; m >= 1; m >>= 1) s0 += __shfl_xor(s0, m, 64);
            if (l31 == 0) out[(size_t)(row0 + prow) * TT + t] = s0 + blin;
        }
    }
}

extern "C" void kernel_launch(void* const* d_in, const int* in_sizes, int n_in,
                              void* d_out, int out_size, void* d_ws, size_t ws_size,
                              hipStream_t stream) {
    const float* x     = (const float*)d_in[0];
    const float* W_ih  = (const float*)d_in[1];
    const float* W_hh  = (const float*)d_in[2];
    const float* b_ih  = (const float*)d_in[3];
    const float* b_hh  = (const float*)d_in[4];
    const float* W_lin = (const float*)d_in[5];
    const float* b_lin = (const float*)d_in[6];
    float* out = (float*)d_out;
    gru_kernel<<<32, 512, 0, stream>>>(x, W_ih, W_hh, b_ih, b_hh, W_lin, b_lin, out);
}

// Round 4
// 888.152 us; speedup vs baseline: 1.1662x; 1.1662x over previous
//
#include <hip/hip_runtime.h>

#define TT 512
#define II 8
#define HH 256
#define ST 296   // padded LDS row stride (halfs): 592B = 16*37, breaks pow2 bank patterns
#define RR 8     // batch rows per block
#define NB 64    // blocks = 512 / RR

typedef _Float16 h4_t  __attribute__((ext_vector_type(4)));
typedef _Float16 h8_t  __attribute__((ext_vector_type(8)));
typedef float    f32x4 __attribute__((ext_vector_type(4)));

__device__ inline h8_t cvt8(const float* __restrict__ p, float s) {
    h8_t r;
#pragma unroll
    for (int i = 0; i < 8; ++i) r[i] = (_Float16)(p[i] * s);
    return r;
}

// R5: RR=8 rows/block over 64 blocks (2x CUs vs R2/R3), dense gate math with
// NO cross-lane ops. R4's permlane pack failed correctness (inline-asm
// permlane hazards are invisible to the compiler's hazard recognizer).
// Replacement: DUPLICATE-ROW trick. hbuf rows 8-15 mirror rows 0-7 (each
// lane writes h twice), so every MFMA chain's C/D rows 8-15 are exact copies
// of rows 0-7 -> group-1 results are natively in lanes 32-63. The "pack" is
// 16 branchless v_cndmask (lane<32 ? acc0 : acc1). 12 trans/wave/step.
// W_hh: 4 chains (R0,Z0,N0,R1 = 128 regs) in registers/AGPRs, 2 chains
// (Z1,N1) in 128KB lane-private LDS pools -> arch VGPR demand ~100 < 128,
// no scratch spill (R2/R3 both spilled in-loop; WRITE_SIZE showed it).
// LDS: 18.5K hbuf + 128K pools = 146.5K < 160K. 1 block/CU, persistent.
__global__ void __launch_bounds__(512, 2) gru_kernel(
    const float* __restrict__ x,    const float* __restrict__ W_ih,
    const float* __restrict__ W_hh, const float* __restrict__ b_ih,
    const float* __restrict__ b_hh, const float* __restrict__ W_lin,
    const float* __restrict__ b_lin, float* __restrict__ out)
{
    __shared__ _Float16 hbuf[2][16][ST];
    __shared__ h8_t wz1buf[8 * 8 * 64];   // 64 KiB: group-1 Z-gate W frags, lane-private
    __shared__ h8_t wn1buf[8 * 8 * 64];   // 64 KiB: group-1 N-gate W frags, lane-private

    const int tid  = threadIdx.x;
    const int w    = tid >> 6;     // wave 0..7
    const int lane = tid & 63;
    const int q    = lane >> 4;    // quad 0..3
    const int r15  = lane & 15;
    const int row0 = blockIdx.x * RR;

    // scales fold log2(e) into the weights:
    //   sigmoid(a) = rcp(1 + exp2(-a*log2e));  tanh(y) = 1 - 2*rcp(1 + exp2(2y*log2e))
    const float sRZ = -1.44269504088896340736f;
    const float sN  =  2.88539008177792681472f;

    // wave w owns gate columns [32w, 32w+32): col-groups g=0 (lanes 0-31 use
    // C rows 0-7) and g=1 (lanes 32-63 use C rows 8-15 = duplicates of 0-7).
    const int c0 = w * 32 + r15;
    const int c1 = c0 + 16;

    // ---- W_hh -> B-fragments (16x16x32_f16: lane holds B[n=lane&15][k=q*8+j]) ----
    h8_t wfR0[8], wfZ0[8], wfN0[8], wfR1[8];
#pragma unroll
    for (int s = 0; s < 8; ++s) {
        const int k0 = s * 32 + q * 8;
        wfR0[s] = cvt8(W_hh + (size_t)(c0)       * HH + k0, sRZ);
        wfZ0[s] = cvt8(W_hh + (size_t)(256 + c0) * HH + k0, sRZ);
        wfN0[s] = cvt8(W_hh + (size_t)(512 + c0) * HH + k0, sN);
        wfR1[s] = cvt8(W_hh + (size_t)(c1)       * HH + k0, sRZ);
        wz1buf[(w * 8 + s) * 64 + lane] = cvt8(W_hh + (size_t)(256 + c1) * HH + k0, sRZ);
        wn1buf[(w * 8 + s) * 64 + lane] = cvt8(W_hh + (size_t)(512 + c1) * HH + k0, sN);
    }
    // ---- x-part B-fragments (16x16x16f16) over [x(8)|bias(1)|0..] for both groups ----
    h4_t xfR[2], xfZ[2], xfN[2];
#pragma unroll
    for (int g = 0; g < 2; ++g) {
        const int cR = g ? c1 : c0;
#pragma unroll
        for (int j = 0; j < 4; ++j) {
            const int kp = q * 4 + j;
            float vR = 0.f, vZ = 0.f, vN = 0.f;
            if (kp < 8) {
                vR = W_ih[(cR)       * II + kp] * sRZ;
                vZ = W_ih[(256 + cR) * II + kp] * sRZ;
                vN = W_ih[(512 + cR) * II + kp] * sN;
            } else if (kp == 8) {
                vR = (b_ih[cR]       + b_hh[cR])       * sRZ;
                vZ = (b_ih[256 + cR] + b_hh[256 + cR]) * sRZ;
                vN = b_ih[512 + cR] * sN;   // b_hh_n rides inside r*(.), kept separate
            }
            xfR[g][j] = (_Float16)vR; xfZ[g][j] = (_Float16)vZ; xfN[g][j] = (_Float16)vN;
        }
    }
    // per-lane gate constants: lanes 0-31 -> col c0, lanes 32-63 -> col c1
    const bool hi = (lane >= 32);
    const float bhnp = (hi ? b_hh[512 + c1] : b_hh[512 + c0]) * sN;
    const float blin = b_lin[0];
    // pred weights in regs: lane holds W_lin[4*lane .. +3]
    const float wl0 = W_lin[lane * 4 + 0], wl1 = W_lin[lane * 4 + 1];
    const float wl2 = W_lin[lane * 4 + 2], wl3 = W_lin[lane * 4 + 3];

    // ---- LDS init: zero both h buffers, bias-one at k=264 (all 16 rows),
    //      x_0 into buf0 rows 0-7 AND mirrored rows 8-15 ----
    for (int i = tid; i < 2 * 16 * ST; i += 512) (&hbuf[0][0][0])[i] = (_Float16)0.f;
    __syncthreads();
    if (tid < 32) hbuf[tid >> 4][tid & 15][264] = (_Float16)1.f;
    if (tid < 64) {
        const int rr_ = tid >> 3, ii = tid & 7;
        const _Float16 xh = (_Float16)x[((size_t)(row0 + rr_) * TT + 0) * II + ii];
        hbuf[0][rr_][256 + ii]     = xh;
        hbuf[0][rr_ + 8][256 + ii] = xh;    // mirror
    }
    __syncthreads();

    const h8_t* __restrict__ wz_lane = &wz1buf[w * 8 * 64 + lane];
    const h8_t* __restrict__ wn_lane = &wn1buf[w * 8 * 64 + lane];

    f32x4 hreg = {0.f, 0.f, 0.f, 0.f};   // h at (row rb+j, col colp)
    const f32x4 z4 = {0.f, 0.f, 0.f, 0.f};

    // packed output coordinates: actual row base = (q&1)*4, col = c0 or c1
    const int rb   = (q & 1) * 4;
    const int colp = hi ? c1 : c0;

    for (int t = 0; t < TT; ++t) {
        const int cur = t & 1, nxt = cur ^ 1;

        // prefetch x_{t+1}: lanes 0-7 carry row w's 8 inputs
        float xv = 0.f;
        {
            const int tn = (t + 1 < TT) ? t + 1 : TT - 1;
            if (lane < II) xv = x[((size_t)(row0 + w) * TT + tn) * II + lane];
        }

        // A-fragments from LDS (A[m=lane&15][k=q*8+j]); 6 fused chains share A.
        // A rows 8-15 are duplicates of rows 0-7, so C rows 8-15 (lanes 32-63)
        // duplicate C rows 0-7 for every chain.
        const _Float16* hb = &hbuf[cur][r15][0];
        const h4_t a2 = *(const h4_t*)(hb + 256 + q * 4);
        f32x4 accR0 = __builtin_amdgcn_mfma_f32_16x16x16f16(a2, xfR[0], z4, 0, 0, 0);
        f32x4 accZ0 = __builtin_amdgcn_mfma_f32_16x16x16f16(a2, xfZ[0], z4, 0, 0, 0);
        f32x4 gin0  = __builtin_amdgcn_mfma_f32_16x16x16f16(a2, xfN[0], z4, 0, 0, 0);
        f32x4 accR1 = __builtin_amdgcn_mfma_f32_16x16x16f16(a2, xfR[1], z4, 0, 0, 0);
        f32x4 accZ1 = __builtin_amdgcn_mfma_f32_16x16x16f16(a2, xfZ[1], z4, 0, 0, 0);
        f32x4 gin1  = __builtin_amdgcn_mfma_f32_16x16x16f16(a2, xfN[1], z4, 0, 0, 0);
        f32x4 accN0 = z4, accN1 = z4;
#pragma unroll
        for (int s = 0; s < 8; ++s) {
            const h8_t a  = *(const h8_t*)(hb + s * 32 + q * 8);   // shared by all 6 chains
            const h8_t wz = wz_lane[s * 64];                       // lane-private b128
            const h8_t wn = wn_lane[s * 64];
            accR0 = __builtin_amdgcn_mfma_f32_16x16x32_f16(a, wfR0[s], accR0, 0, 0, 0);
            accZ0 = __builtin_amdgcn_mfma_f32_16x16x32_f16(a, wfZ0[s], accZ0, 0, 0, 0);
            accN0 = __builtin_amdgcn_mfma_f32_16x16x32_f16(a, wfN0[s], accN0, 0, 0, 0);
            accR1 = __builtin_amdgcn_mfma_f32_16x16x32_f16(a, wfR1[s], accR1, 0, 0, 0);
            accZ1 = __builtin_amdgcn_mfma_f32_16x16x32_f16(a, wz,     accZ1, 0, 0, 0);
            accN1 = __builtin_amdgcn_mfma_f32_16x16x32_f16(a, wn,     accN1, 0, 0, 0);
        }

        // pred_{t-1} = h_{t-1} . W_lin + b_lin from hbuf[cur] (overlaps MFMA drain).
        // wave w reduces row w (RR=8 rows <-> 8 waves).
        if (t > 0) {
            const h4_t hv4 = *(const h4_t*)&hbuf[cur][w][lane * 4];
            float s0 = (float)hv4[0] * wl0 + (float)hv4[1] * wl1
                     + (float)hv4[2] * wl2 + (float)hv4[3] * wl3;
#pragma unroll
            for (int m = 32; m >= 1; m >>= 1) s0 += __shfl_xor(s0, m, 64);
            if (lane == 0) out[(size_t)(row0 + w) * TT + (t - 1)] = s0 + blin;
        }

        // gates, dense: lanes 0-31 use group-0 accs, lanes 32-63 group-1
        // (v_cndmask select, no cross-lane). 12 trans/wave/step.
        _Float16* hw = &hbuf[nxt][rb][colp];
#pragma unroll
        for (int j = 0; j < 4; ++j) {
            const float vR = hi ? accR1[j] : accR0[j];
            const float vZ = hi ? accZ1[j] : accZ0[j];
            const float vN = hi ? accN1[j] : accN0[j];
            const float vG = hi ? gin1[j]  : gin0[j];
            const float rr = __builtin_amdgcn_rcpf(1.f + __builtin_amdgcn_exp2f(vR));
            const float zz = __builtin_amdgcn_rcpf(1.f + __builtin_amdgcn_exp2f(vZ));
            const float u  = vG + rr * (vN + bhnp);
            const float nn = 1.f - 2.f * __builtin_amdgcn_rcpf(1.f + __builtin_amdgcn_exp2f(u));
            const float hv = nn + zz * (hreg[j] - nn);
            hreg[j] = hv;
            const _Float16 hh = (_Float16)hv;
            hw[j * ST]          = hh;   // hbuf[nxt][rb+j][colp]
            hw[j * ST + 8 * ST] = hh;   // mirror row rb+j+8
        }
        if (lane < II) {
            const _Float16 xh = (_Float16)xv;
            hbuf[nxt][w][256 + lane]     = xh;
            hbuf[nxt][w + 8][256 + lane] = xh;  // mirror
        }

        __syncthreads();   // single barrier per step
    }

    // final pred for t = TT-1 (h_final sits in hbuf[TT & 1] = hbuf[0])
    {
        const h4_t hv4 = *(const h4_t*)&hbuf[TT & 1][w][lane * 4];
        float s0 = (float)hv4[0] * wl0 + (float)hv4[1] * wl1
                 + (float)hv4[2] * wl2 + (float)hv4[3] * wl3;
#pragma unroll
        for (int m = 32; m >= 1; m >>= 1) s0 += __shfl_xor(s0, m, 64);
        if (lane == 0) out[(size_t)(row0 + w) * TT + (TT - 1)] = s0 + blin;
    }
}

extern "C" void kernel_launch(void* const* d_in, const int* in_sizes, int n_in,
                              void* d_out, int out_size, void* d_ws, size_t ws_size,
                              hipStream_t stream) {
    const float* x     = (const float*)d_in[0];
    const float* W_ih  = (const float*)d_in[1];
    const float* W_hh  = (const float*)d_in[2];
    const float* b_ih  = (const float*)d_in[3];
    const float* b_hh  = (const float*)d_in[4];
    const float* W_lin = (const float*)d_in[5];
    const float* b_lin = (const float*)d_in[6];
    float* out = (float*)d_out;
    gru_kernel<<<NB, 512, 0, stream>>>(x, W_ih, W_hh, b_ih, b_hh, W_lin, b_lin, out);
}

// Round 5
// 886.471 us; speedup vs baseline: 1.1684x; 1.0019x over previous
//
#include <hip/hip_runtime.h>

#define TT 512
#define II 8
#define HH 256
#define ST 296   // padded LDS row stride (halfs): 592B = 16*37, breaks pow2 bank patterns
#define RR 8     // batch rows per block
#define NB 64    // blocks = 512 / RR
#define XSR 136  // xstage row stride in halfs (272B = 68 dwords -> rows hit distinct bank pairs)

typedef _Float16 h4_t  __attribute__((ext_vector_type(4)));
typedef _Float16 h8_t  __attribute__((ext_vector_type(8)));
typedef float    f32x2 __attribute__((ext_vector_type(2)));
typedef float    f32x4 __attribute__((ext_vector_type(4)));

__device__ inline h8_t cvt8(const float* __restrict__ p, float s) {
    h8_t r;
#pragma unroll
    for (int i = 0; i < 8; ++i) r[i] = (_Float16)(p[i] * s);
    return r;
}

// R6: kill the in-loop global-memory dependencies. R5 evidence (2x CUs, half
// per-CU work -> only -13% time) says the loop is LATENCY-bound: per-SIMD busy
// ~1450 cyc/step vs 4055 measured. The barrier's implied vmcnt(0) drained
// (a) the per-step x global load (~200-900 cyc) and (b) the per-step scattered
// 4B pred store (also the 8.4MB WRITE_SIZE: partial-line writebacks).
//  - x staged in LDS, 16-step double-buffered windows: refill load issues at
//    window start, cvt+ds_write 15 steps later -> latency fully hidden. The
//    a2 A-frag's x/bias part reads xstage + compile-time consts.
//  - pred -> LDS ring predbuf[2][8][64], flushed as ONE coalesced 2KB store
//    per 64 steps (parity double-buffer avoids flush/overwrite races).
// MFMA/gate core is byte-identical to the verified R5 kernel.
// LDS: 18.5K hbuf + 128K W pools + 4.25K xstage + 4K predbuf = 158.5K < 160K.
__global__ void __launch_bounds__(512, 2) gru_kernel(
    const float* __restrict__ x,    const float* __restrict__ W_ih,
    const float* __restrict__ W_hh, const float* __restrict__ b_ih,
    const float* __restrict__ b_hh, const float* __restrict__ W_lin,
    const float* __restrict__ b_lin, float* __restrict__ out)
{
    __shared__ _Float16 hbuf[2][16][ST];
    __shared__ h8_t wz1buf[8 * 8 * 64];     // 64 KiB: group-1 Z-gate W frags, lane-private
    __shared__ h8_t wn1buf[8 * 8 * 64];     // 64 KiB: group-1 N-gate W frags, lane-private
    __shared__ _Float16 xstage[2][RR][XSR]; // x windows: [win][row][t16*8+i], padded rows
    __shared__ float predbuf[2][RR][64];    // pred ring, parity by (p>>6)&1

    const int tid  = threadIdx.x;
    const int w    = tid >> 6;     // wave 0..7
    const int lane = tid & 63;
    const int q    = lane >> 4;    // quad 0..3
    const int r15  = lane & 15;
    const int row0 = blockIdx.x * RR;

    // scales fold log2(e) into the weights:
    //   sigmoid(a) = rcp(1 + exp2(-a*log2e));  tanh(y) = 1 - 2*rcp(1 + exp2(2y*log2e))
    const float sRZ = -1.44269504088896340736f;
    const float sN  =  2.88539008177792681472f;

    // wave w owns gate columns [32w, 32w+32): g=0 (lanes 0-31, C rows 0-7),
    // g=1 (lanes 32-63, C rows 8-15 = duplicates of rows 0-7).
    const int c0 = w * 32 + r15;
    const int c1 = c0 + 16;

    // ---- W_hh -> B-fragments (16x16x32_f16: lane holds B[n=lane&15][k=q*8+j]) ----
    h8_t wfR0[8], wfZ0[8], wfN0[8], wfR1[8];
#pragma unroll
    for (int s = 0; s < 8; ++s) {
        const int k0 = s * 32 + q * 8;
        wfR0[s] = cvt8(W_hh + (size_t)(c0)       * HH + k0, sRZ);
        wfZ0[s] = cvt8(W_hh + (size_t)(256 + c0) * HH + k0, sRZ);
        wfN0[s] = cvt8(W_hh + (size_t)(512 + c0) * HH + k0, sN);
        wfR1[s] = cvt8(W_hh + (size_t)(c1)       * HH + k0, sRZ);
        wz1buf[(w * 8 + s) * 64 + lane] = cvt8(W_hh + (size_t)(256 + c1) * HH + k0, sRZ);
        wn1buf[(w * 8 + s) * 64 + lane] = cvt8(W_hh + (size_t)(512 + c1) * HH + k0, sN);
    }
    // ---- x-part B-fragments (16x16x16f16) over [x(8)|bias(1)|0..] for both groups ----
    h4_t xfR[2], xfZ[2], xfN[2];
#pragma unroll
    for (int g = 0; g < 2; ++g) {
        const int cR = g ? c1 : c0;
#pragma unroll
        for (int j = 0; j < 4; ++j) {
            const int kp = q * 4 + j;
            float vR = 0.f, vZ = 0.f, vN = 0.f;
            if (kp < 8) {
                vR = W_ih[(cR)       * II + kp] * sRZ;
                vZ = W_ih[(256 + cR) * II + kp] * sRZ;
                vN = W_ih[(512 + cR) * II + kp] * sN;
            } else if (kp == 8) {
                vR = (b_ih[cR]       + b_hh[cR])       * sRZ;
                vZ = (b_ih[256 + cR] + b_hh[256 + cR]) * sRZ;
                vN = b_ih[512 + cR] * sN;   // b_hh_n rides inside r*(.), kept separate
            }
            xfR[g][j] = (_Float16)vR; xfZ[g][j] = (_Float16)vZ; xfN[g][j] = (_Float16)vN;
        }
    }
    // per-lane gate constants: lanes 0-31 -> col c0, lanes 32-63 -> col c1
    const bool hi = (lane >= 32);
    const float bhnp = (hi ? b_hh[512 + c1] : b_hh[512 + c0]) * sN;
    const float blin = b_lin[0];
    // pred weights in regs: lane holds W_lin[4*lane .. +3]
    const float wl0 = W_lin[lane * 4 + 0], wl1 = W_lin[lane * 4 + 1];
    const float wl2 = W_lin[lane * 4 + 2], wl3 = W_lin[lane * 4 + 3];

    // A-frag constants for the x-part (k'=q*4+j): q=2 holds bias-one at k'=8
    const h4_t bias4 = {(_Float16)1.f, (_Float16)0.f, (_Float16)0.f, (_Float16)0.f};
    const h4_t zero4 = {(_Float16)0.f, (_Float16)0.f, (_Float16)0.f, (_Float16)0.f};

    // ---- LDS init: zero h buffers; preload x window 0 (steps 0..15) ----
    for (int i = tid; i < 2 * 16 * ST; i += 512) (&hbuf[0][0][0])[i] = (_Float16)0.f;
    {
        // 512 threads x 2 floats cover 8 rows x 16 steps x 8 inputs
        const int rr_ = tid >> 6, f2 = (tid & 63) * 2;
        const f32x2 v = *(const f32x2*)(x + (size_t)(row0 + rr_) * TT * II + f2);
        xstage[0][rr_][f2]     = (_Float16)v[0];
        xstage[0][rr_][f2 + 1] = (_Float16)v[1];
    }
    __syncthreads();

    const h8_t* __restrict__ wz_lane = &wz1buf[w * 8 * 64 + lane];
    const h8_t* __restrict__ wn_lane = &wn1buf[w * 8 * 64 + lane];

    f32x4 hreg = {0.f, 0.f, 0.f, 0.f};   // h at (row rb+j, col colp)
    const f32x4 z4 = {0.f, 0.f, 0.f, 0.f};

    // packed output coordinates: actual row base = (q&1)*4, col = c0 or c1
    const int rb   = (q & 1) * 4;
    const int colp = hi ? c1 : c0;

    // x refill staging registers (persist across the 16-step window)
    f32x2 xpre = {0.f, 0.f};
    const int xrow = tid >> 6, xf2 = (tid & 63) * 2;

    for (int t = 0; t < TT; ++t) {
        const int cur = t & 1, nxt = cur ^ 1;
        const int win = (t >> 4) & 1;

        // x window refill: issue load at window start, consumed 15 steps later
        if ((t & 15) == 0 && t + 16 < TT) {
            xpre = *(const f32x2*)(x + ((size_t)(row0 + xrow) * TT + (t + 16)) * II + xf2);
        }

        // A-fragments: h-part from hbuf (rows 8-15 duplicate 0-7), x/bias part
        // from xstage + constants. 6 fused chains share A.
        const _Float16* hb = &hbuf[cur][r15][0];
        const h4_t xa = *(const h4_t*)&xstage[win][r15 & 7][(t & 15) * 8 + (q & 1) * 4];
        const h4_t a2 = (q < 2) ? xa : ((q == 2) ? bias4 : zero4);
        f32x4 accR0 = __builtin_amdgcn_mfma_f32_16x16x16f16(a2, xfR[0], z4, 0, 0, 0);
        f32x4 accZ0 = __builtin_amdgcn_mfma_f32_16x16x16f16(a2, xfZ[0], z4, 0, 0, 0);
        f32x4 gin0  = __builtin_amdgcn_mfma_f32_16x16x16f16(a2, xfN[0], z4, 0, 0, 0);
        f32x4 accR1 = __builtin_amdgcn_mfma_f32_16x16x16f16(a2, xfR[1], z4, 0, 0, 0);
        f32x4 accZ1 = __builtin_amdgcn_mfma_f32_16x16x16f16(a2, xfZ[1], z4, 0, 0, 0);
        f32x4 gin1  = __builtin_amdgcn_mfma_f32_16x16x16f16(a2, xfN[1], z4, 0, 0, 0);
        f32x4 accN0 = z4, accN1 = z4;
#pragma unroll
        for (int s = 0; s < 8; ++s) {
            const h8_t a  = *(const h8_t*)(hb + s * 32 + q * 8);   // shared by all 6 chains
            const h8_t wz = wz_lane[s * 64];                       // lane-private b128
            const h8_t wn = wn_lane[s * 64];
            accR0 = __builtin_amdgcn_mfma_f32_16x16x32_f16(a, wfR0[s], accR0, 0, 0, 0);
            accZ0 = __builtin_amdgcn_mfma_f32_16x16x32_f16(a, wfZ0[s], accZ0, 0, 0, 0);
            accN0 = __builtin_amdgcn_mfma_f32_16x16x32_f16(a, wfN0[s], accN0, 0, 0, 0);
            accR1 = __builtin_amdgcn_mfma_f32_16x16x32_f16(a, wfR1[s], accR1, 0, 0, 0);
            accZ1 = __builtin_amdgcn_mfma_f32_16x16x32_f16(a, wz,     accZ1, 0, 0, 0);
            accN1 = __builtin_amdgcn_mfma_f32_16x16x32_f16(a, wn,     accN1, 0, 0, 0);
        }

        // pred_{t-1} = h_{t-1}.W_lin + b_lin from hbuf[cur] (overlaps MFMA drain);
        // goes to the LDS ring, not global.
        if (t > 0) {
            const h4_t hv4 = *(const h4_t*)&hbuf[cur][w][lane * 4];
            float s0 = (float)hv4[0] * wl0 + (float)hv4[1] * wl1
                     + (float)hv4[2] * wl2 + (float)hv4[3] * wl3;
#pragma unroll
            for (int m = 32; m >= 1; m >>= 1) s0 += __shfl_xor(s0, m, 64);
            if (lane == 0) predbuf[((t - 1) >> 6) & 1][w][(t - 1) & 63] = s0 + blin;
        }

        // gates, dense: lanes 0-31 use group-0 accs, lanes 32-63 group-1.
        _Float16* hw = &hbuf[nxt][rb][colp];
#pragma unroll
        for (int j = 0; j < 4; ++j) {
            const float vR = hi ? accR1[j] : accR0[j];
            const float vZ = hi ? accZ1[j] : accZ0[j];
            const float vN = hi ? accN1[j] : accN0[j];
            const float vG = hi ? gin1[j]  : gin0[j];
            const float rr = __builtin_amdgcn_rcpf(1.f + __builtin_amdgcn_exp2f(vR));
            const float zz = __builtin_amdgcn_rcpf(1.f + __builtin_amdgcn_exp2f(vZ));
            const float u  = vG + rr * (vN + bhnp);
            const float nn = 1.f - 2.f * __builtin_amdgcn_rcpf(1.f + __builtin_amdgcn_exp2f(u));
            const float hv = nn + zz * (hreg[j] - nn);
            hreg[j] = hv;
            const _Float16 hh = (_Float16)hv;
            hw[j * ST]          = hh;   // hbuf[nxt][rb+j][colp]
            hw[j * ST + 8 * ST] = hh;   // mirror row rb+j+8
        }

        // x window writeback: cvt + ds_write into the other buffer, 15 steps
        // after the load was issued (vmcnt wait lands here, fully hidden)
        if ((t & 15) == 15 && t + 1 < TT) {
            _Float16* xd = &xstage[win ^ 1][xrow][xf2];
            xd[0] = (_Float16)xpre[0];
            xd[1] = (_Float16)xpre[1];
        }

        __syncthreads();   // single barrier per step; drains no global traffic

        // coalesced pred flush: one 2KB store per 64 steps
        if ((t & 63) == 0 && t > 0) {
            const int pb = ((t >> 6) & 1) ^ 1;
            out[(size_t)(row0 + (tid >> 6)) * TT + (t - 64) + (tid & 63)] =
                predbuf[pb][tid >> 6][tid & 63];
        }
    }

    // final pred for t = TT-1 (h_final sits in hbuf[TT & 1] = hbuf[0])
    {
        const h4_t hv4 = *(const h4_t*)&hbuf[TT & 1][w][lane * 4];
        float s0 = (float)hv4[0] * wl0 + (float)hv4[1] * wl1
                 + (float)hv4[2] * wl2 + (float)hv4[3] * wl3;
#pragma unroll
        for (int m = 32; m >= 1; m >>= 1) s0 += __shfl_xor(s0, m, 64);
        if (lane == 0) predbuf[1][w][63] = s0 + blin;
    }
    __syncthreads();
    // flush last chunk [448, 512)
    out[(size_t)(row0 + (tid >> 6)) * TT + 448 + (tid & 63)] =
        predbuf[1][tid >> 6][tid & 63];
}

extern "C" void kernel_launch(void* const* d_in, const int* in_sizes, int n_in,
                              void* d_out, int out_size, void* d_ws, size_t ws_size,
                              hipStream_t stream) {
    const float* x     = (const float*)d_in[0];
    const float* W_ih  = (const float*)d_in[1];
    const float* W_hh  = (const float*)d_in[2];
    const float* b_ih  = (const float*)d_in[3];
    const float* b_hh  = (const float*)d_in[4];
    const float* W_lin = (const float*)d_in[5];
    const float* b_lin = (const float*)d_in[6];
    float* out = (float*)d_out;
    gru_kernel<<<NB, 512, 0, stream>>>(x, W_ih, W_hh, b_ih, b_hh, W_lin, b_lin, out);
}